// Round 5
// baseline (318.491 us; speedup 1.0000x reference)
//
#include <hip/hip_runtime.h>

typedef _Float16 f16;
typedef f16 f16x4 __attribute__((ext_vector_type(4)));
typedef f16 f16x8 __attribute__((ext_vector_type(8)));
typedef float f32x4 __attribute__((ext_vector_type(4)));

#define B_ 4
#define S_ 2048
#define D_ 768
#define H_ 12
#define DK_ 64

// async global->LDS DMA, 16 B per lane. LDS dest = wave-uniform base + lane*16.
__device__ __forceinline__ void dma16(const f16* g, f16* l) {
    __builtin_amdgcn_global_load_lds(
        (__attribute__((address_space(1))) void*)(uintptr_t)g,
        (__attribute__((address_space(3))) void*)l, 16, 0, 0);
}

// ---------------------------------------------------------------------------
// fused fp32 -> fp16 conversion for 7 tensors (q,k,v,Wq,Wk,Wv,Wo)
// ---------------------------------------------------------------------------
struct Cvt7 { const float* s[7]; f16* d[7]; int n[7]; };

__global__ __launch_bounds__(256) void cvt7_kernel(Cvt7 a)
{
    const int z = blockIdx.y;
    int i = (blockIdx.x * 256 + threadIdx.x) * 8;
    if (i >= a.n[z]) return;
    const float* __restrict__ s = a.s[z];
    float4 x = *(const float4*)(s + i);
    float4 y = *(const float4*)(s + i + 4);
    f16x8 h = {(f16)x.x, (f16)x.y, (f16)x.z, (f16)x.w,
               (f16)y.x, (f16)y.y, (f16)y.z, (f16)y.w};
    *(f16x8*)(a.d[z] + i) = h;
}

// ---------------------------------------------------------------------------
// C = (A[M,K] @ W[N,K]^T + bias) * scale.  fp16 operands, global_load_lds
// staging, DOUBLE-BUFFERED BK=32 K-loop with ONE barrier per iter:
//   iter t: barrier; dma(t+1 -> other buf); mfma on buf t&1
// so the staging DMA is in flight across a full compute interval.
// 128x128 tile, 4 waves (2x2), mfma 16x16x32_f16. 2-bit XOR row-swizzle
// keeps frag ds_read_b128 at 2-way (free).
// mode 0: f16 row-major out; mode 1: f16 transposed out [B][D][S] (for V);
// mode 2: f32 row-major out.
// ---------------------------------------------------------------------------
struct GemmArgs { const f16* A; const f16* W; const float* bias; float scale; void* C; int mode; };
struct GemmArgs3 { GemmArgs g[3]; };

__global__ __launch_bounds__(256, 4) void gemm_k(GemmArgs3 args)
{
    const int z = blockIdx.z;
    const f16* __restrict__ A = args.g[z].A;
    const f16* __restrict__ W = args.g[z].W;
    const float* __restrict__ bias = args.g[z].bias;
    const float scale = args.g[z].scale;
    const int mode = args.g[z].mode;

    __shared__ __align__(16) f16 As[2][128 * 32];   // 8 KB each
    __shared__ __align__(16) f16 Bs[2][128 * 32];   // total 32 KB

    const int tid = threadIdx.x, lane = tid & 63, w = tid >> 6;
    const int l15 = lane & 15, lg = lane >> 4;
    const int wm = (w >> 1) * 64, wn = (w & 1) * 64;
    const int m0 = blockIdx.y * 128, n0 = blockIdx.x * 128;

    // staging: dma-op (w,c) covers rows (w*2+c)*16 + (lane>>2); phys chunk
    // lane&3 holds global chunk (lane&3) ^ rsw(row), rsw(r)=(r&3)^((r>>2)&3).
    const int r16 = lane >> 2;
    const int rswS = (r16 & 3) ^ ((r16 >> 2) & 3);
    const int gch = (lane & 3) ^ rswS;
    const f16* gA = A + (size_t)(m0 + w * 32 + r16) * D_ + gch * 8;
    const f16* gB = W + (size_t)(n0 + w * 32 + r16) * D_ + gch * 8;
    const int rs15 = (l15 & 3) ^ ((l15 >> 2) & 3);   // read-side swizzle

    f32x4 acc[4][4] = {};
    const int NIT = D_ / 32;   // 24

    // prefetch iter 0 into buf 0
#pragma unroll
    for (int c = 0; c < 2; ++c) {
        dma16(gA + (size_t)(c * 16) * D_, &As[0][(w * 2 + c) * 512]);
        dma16(gB + (size_t)(c * 16) * D_, &Bs[0][(w * 2 + c) * 512]);
    }

    for (int t = 0; t < NIT; ++t) {
        __syncthreads();   // drains dma(t) + prior frag reads of other buf
        if (t + 1 < NIT) {
            const int kt = (t + 1) * 32, nb = (t + 1) & 1;
#pragma unroll
            for (int c = 0; c < 2; ++c) {
                dma16(gA + (size_t)(c * 16) * D_ + kt, &As[nb][(w * 2 + c) * 512]);
                dma16(gB + (size_t)(c * 16) * D_ + kt, &Bs[nb][(w * 2 + c) * 512]);
            }
        }
        const int cb = t & 1;
        f16x8 af[4], bf[4];
#pragma unroll
        for (int i = 0; i < 4; ++i)
            af[i] = *(const f16x8*)&As[cb][(wm + i * 16 + l15) * 32 + ((lg ^ rs15) * 8)];
#pragma unroll
        for (int j = 0; j < 4; ++j)
            bf[j] = *(const f16x8*)&Bs[cb][(wn + j * 16 + l15) * 32 + ((lg ^ rs15) * 8)];
#pragma unroll
        for (int i = 0; i < 4; ++i)
#pragma unroll
            for (int j = 0; j < 4; ++j)
                acc[i][j] = __builtin_amdgcn_mfma_f32_16x16x32_f16(
                    af[i], bf[j], acc[i][j], 0, 0, 0);
    }

    if (mode == 1) {
        // V^T: out[(b*D_ + col)*S_ + s_local]; 4 consecutive s per lane.
#pragma unroll
        for (int j = 0; j < 4; ++j) {
            int col = n0 + wn + j * 16 + l15;
            float bb = bias[col];
#pragma unroll
            for (int i = 0; i < 4; ++i) {
                int row = m0 + wm + i * 16 + lg * 4;
                int bI = row >> 11, sl = row & (S_ - 1);
                f16x4 o = {(f16)(acc[i][j][0] + bb), (f16)(acc[i][j][1] + bb),
                           (f16)(acc[i][j][2] + bb), (f16)(acc[i][j][3] + bb)};
                *(f16x4*)&((f16*)args.g[z].C)[((size_t)bI * D_ + col) * S_ + sl] = o;
            }
        }
    } else if (mode == 0) {
#pragma unroll
        for (int j = 0; j < 4; ++j) {
            int col = n0 + wn + j * 16 + l15;
            float bb = bias[col];
#pragma unroll
            for (int i = 0; i < 4; ++i) {
                int row = m0 + wm + i * 16 + lg * 4;
#pragma unroll
                for (int r = 0; r < 4; ++r)
                    ((f16*)args.g[z].C)[(size_t)(row + r) * D_ + col] =
                        (f16)((acc[i][j][r] + bb) * scale);
            }
        }
    } else {
#pragma unroll
        for (int j = 0; j < 4; ++j) {
            int col = n0 + wn + j * 16 + l15;
            float bb = bias[col];
#pragma unroll
            for (int i = 0; i < 4; ++i) {
                int row = m0 + wm + i * 16 + lg * 4;
#pragma unroll
                for (int r = 0; r < 4; ++r)
                    ((float*)args.g[z].C)[(size_t)(row + r) * D_ + col] =
                        acc[i][j][r] + bb;
            }
        }
    }
}

// ---------------------------------------------------------------------------
// Flash attention, double-buffered K/V staging (one barrier per tile).
// Block = 128 q of one (b,h); 4 waves, wave w owns q-cols w*32..+31 of S^T.
// Q (pre-scaled by log2e/8, mask folded) staged into buf1 then hoisted.
// S^T = K·Q^T (16x16x32); P = exp2(S^T) in registers (C-frag == B-frag of
// 16x16x16); out^T += V^T·P; l = ones·P via MFMA (no serial adds/shuffles).
// ---------------------------------------------------------------------------
__global__ __launch_bounds__(256, 2) void attn_k(
    const f16* __restrict__ Qh, const f16* __restrict__ Kh,
    const f16* __restrict__ VhT, const int* __restrict__ mask,
    f16* __restrict__ O)
{
    __shared__ __align__(16) f16 Ks[2][128 * 64];   // 16 KB each
    __shared__ __align__(16) f16 Vt[2][64 * 128];   // 16 KB each; total 64 KB
    const int tid = threadIdx.x, lane = tid & 63, w = tid >> 6;
    const int l15 = lane & 15, lg = lane >> 4;

    // XCD-aware swizzle: 6 consecutive heads per XCD
    const int bid = blockIdx.x;
    const int g8 = bid & 7, j5 = bid >> 3;
    const int head_lin = g8 * 6 + (j5 >> 4);
    const int qt = j5 & 15;
    const int b = head_lin / H_, h = head_lin % H_;
    const int q0 = qt * 128;
    const int rowbase = b * S_;
    const int col0 = h * DK_;

    const int lrow8 = lane >> 3;
    const int lchk8 = (lane & 7) ^ lrow8;

    const f16* Kbase = Kh + (size_t)rowbase * D_ + col0;
    const f16* Vbase = VhT + ((size_t)b * D_ + col0) * S_;
    const int vrow4 = lane >> 4;
    const int vchk = lane & 15;

    // ---- prefetch: Q -> Ks[1]; K,V tile0 -> buf0 ----
    {
        const f16* Qb = Qh + (size_t)(rowbase + q0 + w * 32 + lrow8) * D_ + col0 + lchk8 * 8;
#pragma unroll
        for (int c = 0; c < 4; ++c)
            dma16(Qb + (size_t)(c * 8) * D_, &Ks[1][(w * 4 + c) * 512]);
#pragma unroll
        for (int c = 0; c < 4; ++c)
            dma16(Kbase + (size_t)(w * 32 + c * 8 + lrow8) * D_ + lchk8 * 8,
                  &Ks[0][(w * 4 + c) * 512]);
#pragma unroll
        for (int c = 0; c < 4; ++c) {
            int o = w * 4 + c;
            int drow = o * 4 + vrow4;
            dma16(Vbase + (size_t)drow * S_ + (vchk ^ (drow & 15)) * 8,
                  &Vt[0][o * 512]);
        }
    }
    __syncthreads();   // all prefetch DMA drained

    // hoist Q frags from Ks[1], fold mask
    f16x8 qf[2][2];
#pragma unroll
    for (int ns = 0; ns < 2; ++ns) {
        float mf = (mask[rowbase + q0 + w * 32 + ns * 16 + l15] != 0) ? 1.0f : 0.0f;
#pragma unroll
        for (int kk = 0; kk < 2; ++kk) {
            f16x8 t = *(const f16x8*)&Ks[1][(w * 32 + ns * 16 + l15) * 64 +
                                           (((kk * 4 + lg) ^ (l15 & 7)) * 8)];
#pragma unroll
            for (int e = 0; e < 8; ++e) t[e] = (f16)((float)t[e] * mf);
            qf[ns][kk] = t;
        }
    }
    __syncthreads();   // hoist reads done before tile-1 DMA overwrites Ks[1]

    const f16x4 kones = {(f16)1.f, (f16)1.f, (f16)1.f, (f16)1.f};
    f32x4 acc[4][2] = {};
    f32x4 acc_l[2] = {};

    for (int t = 0; t < S_ / 128; ++t) {
        // prefetch tile t+1 into the other buffer (overlaps this tile's compute)
        if (t + 1 < S_ / 128) {
            const int k0 = (t + 1) * 128, nb = (t + 1) & 1;
#pragma unroll
            for (int c = 0; c < 4; ++c)
                dma16(Kbase + (size_t)(k0 + w * 32 + c * 8 + lrow8) * D_ + lchk8 * 8,
                      &Ks[nb][(w * 4 + c) * 512]);
#pragma unroll
            for (int c = 0; c < 4; ++c) {
                int o = w * 4 + c;
                int drow = o * 4 + vrow4;
                dma16(Vbase + (size_t)drow * S_ + k0 + (vchk ^ (drow & 15)) * 8,
                      &Vt[nb][o * 512]);
            }
        }
        const int cb = t & 1;

        // ---- S^T = K · Q^T ----
        f32x4 sf[8][2] = {};
#pragma unroll
        for (int kk = 0; kk < 2; ++kk) {
            const int chk = ((kk * 4 + lg) ^ (l15 & 7)) * 8;
#pragma unroll
            for (int ms = 0; ms < 8; ++ms) {
                f16x8 kf = *(const f16x8*)&Ks[cb][(ms * 16 + l15) * 64 + chk];
                sf[ms][0] = __builtin_amdgcn_mfma_f32_16x16x32_f16(
                    kf, qf[0][kk], sf[ms][0], 0, 0, 0);
                sf[ms][1] = __builtin_amdgcn_mfma_f32_16x16x32_f16(
                    kf, qf[1][kk], sf[ms][1], 0, 0, 0);
            }
        }

        // ---- P = exp2(s) (log2e folded into Q) ----
        f16x4 pf[8][2];
#pragma unroll
        for (int ns = 0; ns < 2; ++ns)
#pragma unroll
            for (int ms = 0; ms < 8; ++ms) {
                float p0 = __builtin_exp2f(sf[ms][ns][0]);
                float p1 = __builtin_exp2f(sf[ms][ns][1]);
                float p2 = __builtin_exp2f(sf[ms][ns][2]);
                float p3 = __builtin_exp2f(sf[ms][ns][3]);
                pf[ms][ns] = {(f16)p0, (f16)p1, (f16)p2, (f16)p3};
            }

        // ---- out^T += V^T · P ; l += ones · P ----
#pragma unroll
        for (int c = 0; c < 8; ++c) {
            const int pchk = (((c * 2 + (lg >> 1)) ^ l15) * 8) + (lg & 1) * 4;
#pragma unroll
            for (int i = 0; i < 4; ++i) {
                f16x4 vf = *(const f16x4*)&Vt[cb][(i * 16 + l15) * 128 + pchk];
                acc[i][0] = __builtin_amdgcn_mfma_f32_16x16x16f16(
                    vf, pf[c][0], acc[i][0], 0, 0, 0);
                acc[i][1] = __builtin_amdgcn_mfma_f32_16x16x16f16(
                    vf, pf[c][1], acc[i][1], 0, 0, 0);
            }
            acc_l[0] = __builtin_amdgcn_mfma_f32_16x16x16f16(
                kones, pf[c][0], acc_l[0], 0, 0, 0);
            acc_l[1] = __builtin_amdgcn_mfma_f32_16x16x16f16(
                kones, pf[c][1], acc_l[1], 0, 0, 0);
        }

        __syncthreads();   // this tile's LDS reads done + dma(t+1) drained
    }

    // ---- epilogue: out^T frags -> concat[q][d] ----
#pragma unroll
    for (int ns = 0; ns < 2; ++ns) {
        float inv = 1.0f / acc_l[ns][0];
        size_t qrow = (size_t)(rowbase + q0 + w * 32 + ns * 16 + l15);
#pragma unroll
        for (int i = 0; i < 4; ++i) {
            f32x4 o = acc[i][ns] * inv;
            f16x4 ho = {(f16)o[0], (f16)o[1], (f16)o[2], (f16)o[3]};
            *(f16x4*)&O[qrow * D_ + col0 + i * 16 + lg * 4] = ho;
        }
    }
}

extern "C" void kernel_launch(void* const* d_in, const int* in_sizes, int n_in,
                              void* d_out, int out_size, void* d_ws, size_t ws_size,
                              hipStream_t stream)
{
    const float* q    = (const float*)d_in[0];
    const float* k    = (const float*)d_in[1];
    const float* v    = (const float*)d_in[2];
    const int*   mask = (const int*)d_in[3];
    const float* Wq   = (const float*)d_in[4];
    const float* bq   = (const float*)d_in[5];
    const float* Wk   = (const float*)d_in[6];
    const float* bk   = (const float*)d_in[7];
    const float* Wv   = (const float*)d_in[8];
    const float* bv   = (const float*)d_in[9];
    const float* Wo   = (const float*)d_in[10];
    const float* bo   = (const float*)d_in[11];

    const size_t nQKV = (size_t)B_ * S_ * D_;   // 6291456
    const size_t nW   = (size_t)D_ * D_;        // 589824

    f16* qh  = (f16*)d_ws;
    f16* kh  = qh + nQKV;
    f16* vh  = kh + nQKV;
    f16* Wqh = vh + nQKV;
    f16* Wkh = Wqh + nW;
    f16* Wvh = Wkh + nW;
    f16* Woh = Wvh + nW;
    f16* Qp  = Woh + nW;
    f16* Kp  = Qp + nQKV;
    f16* VpT = Kp + nQKV;
    f16* Cp  = VpT + nQKV;

    // 1) convert inputs + weights to fp16
    Cvt7 cv = {{q, k, v, Wq, Wk, Wv, Wo},
               {qh, kh, vh, Wqh, Wkh, Wvh, Woh},
               {(int)nQKV, (int)nQKV, (int)nQKV, (int)nW, (int)nW, (int)nW, (int)nW}};
    cvt7_kernel<<<dim3((int)(nQKV / 8 / 256), 7), 256, 0, stream>>>(cv);

    // 2) fused Q/K/V projections. Q scaled by log2e/8; V written transposed.
    GemmArgs3 g1 = {{{qh, Wqh, bq, 1.44269504f / 8.0f, (void*)Qp, 0},
                     {kh, Wkh, bk, 1.0f, (void*)Kp, 0},
                     {vh, Wvh, bv, 1.0f, (void*)VpT, 1}}};
    gemm_k<<<dim3(6, 64, 3), 256, 0, stream>>>(g1);

    // 3) attention
    attn_k<<<dim3(768), 256, 0, stream>>>(Qp, Kp, VpT, mask, Cp);

    // 4) output projection -> fp32 d_out
    GemmArgs3 g2 = {{{Cp, Woh, bo, 1.0f, d_out, 2},
                     {Cp, Woh, bo, 1.0f, d_out, 2},
                     {Cp, Woh, bo, 1.0f, d_out, 2}}};
    gemm_k<<<dim3(6, 64, 1), 256, 0, stream>>>(g2);
}